// Round 3
// baseline (391.787 us; speedup 1.0000x reference)
//
#include <hip/hip_runtime.h>
#include <hip/hip_bf16.h>
#include <cstdint>
#include <cstddef>

#define B_  32
#define N_  512
#define T_  24
#define F_  64
#define FA_ 74
#define NC  1536   // T_*F_
#define NCF 1776   // T_*FA_

typedef __attribute__((ext_vector_type(8))) short short8;
typedef __attribute__((ext_vector_type(4))) float floatx4;

// ws float-offset layout:
//  [0,74)      rsW ; [128,704) W2' ; [768,1280) sigmoid(alpha)
//  [1536,...)  adjMod bf16[512][512]   (= 0.125*sigma_i*adj, bf16)
//  WS_XT       xT bf16[32][1536][512]
//  WS_E        E  bf16[32][512][1776]  (only if ws big enough)
#define WS_ADJ  1536
#define WS_XT   132608
#define WS_E    12715520
#define WS_BYTES_NEEDED (27264512ULL * 4ULL)

#define AS1(p) ((const __attribute__((address_space(1))) void*)(p))
#define AS3(p) ((__attribute__((address_space(3))) void*)(p))

__device__ __forceinline__ unsigned short f2b(float v) {
  __hip_bfloat16 h = __float2bfloat16(v);
  return *(unsigned short*)&h;
}
__device__ __forceinline__ float b2f(unsigned short u) {
  return __uint_as_float(((unsigned)u) << 16);
}

__global__ __launch_bounds__(256) void params_kernel(
    const float* __restrict__ alpha, const float* __restrict__ w,
    const float* __restrict__ d, const float* __restrict__ w2,
    const float* __restrict__ d2, float* __restrict__ ws) {
  __shared__ float cs[FA_];
  int tid = threadIdx.x;
  if (tid < FA_) {
    float s = 0.f;
    for (int n = 0; n < FA_; ++n) s += w[n * FA_ + tid];
    cs[tid] = s;
  }
  __syncthreads();
  if (tid < FA_) {
    float s = 0.f;
    for (int p = 0; p < FA_; ++p) {
      float dc = fminf(fmaxf(d[p], 0.f), 1.f);
      s += w[tid * FA_ + p] * dc * cs[p];
    }
    ws[tid] = s;
  }
  for (int e = tid; e < T_ * T_; e += 256) {
    int a = e / T_, b = e % T_;
    float s = 0.f;
    for (int p = 0; p < T_; ++p) {
      float dc = fminf(fmaxf(d2[p], 0.f), 1.f);
      s += w2[a * T_ + p] * dc * w2[b * T_ + p];
    }
    ws[128 + e] = s;
  }
  for (int i = tid; i < N_; i += 256) ws[768 + i] = 1.f / (1.f + __expf(-alpha[i]));
}

// adjMod[i,k] = bf16(0.125 * sigma_i * adj[i,k]).  256 blocks x 256 thr x 4 elems.
__global__ __launch_bounds__(256) void convert_adj_kernel(
    const float* __restrict__ adj, float* __restrict__ ws) {
  unsigned short* adjM = (unsigned short*)(ws + WS_ADJ);
  int g = (blockIdx.x * 256 + threadIdx.x) * 4;
  int i = g >> 9;                       // 4 consecutive k within one row i
  float s = 0.125f * ws[768 + i];
  float4 v = *(const float4*)&adj[g];
  ushort4 u;
  u.x = f2b(s * v.x); u.y = f2b(s * v.y); u.z = f2b(s * v.z); u.w = f2b(s * v.w);
  *(ushort4*)&adjM[g] = u;
}

// prep: per (b, 16-node slab): read x once ->
//   (a) xT[b][c][i0:i0+16] bf16
//   (b) E = 0.5x + 0.25*tmix + 0.25*S*rsW  (bf16 to ws if EPATH, fp32 to out if not)
//   (c) aug out cols (EPATH: final relu'd fp32 to out; else embedded in E stream)
// grid (32 slabs, 32 b), 256 threads.
template <bool EPATH>
__global__ __launch_bounds__(256) void prep_kernel(
    const float* __restrict__ x, float* __restrict__ ws, float* __restrict__ out) {
  __shared__ __align__(16) unsigned short xsh[16 * NC];   // 48 KB  [node][c]
  __shared__ __align__(16) float ebuf[4 * NCF];           // 28.4 KB (ushort view if EPATH)
  unsigned short* eh = (unsigned short*)ebuf;

  int tid = threadIdx.x;
  int b = blockIdx.y;
  int i0 = blockIdx.x * 16;
  const float* xb = x + ((size_t)(b * N_ + i0)) * NC;

  // phase 1: load slab (16x1536 fp32), convert, store LDS linear
#pragma unroll
  for (int it = 0; it < 24; ++it) {
    int g = it * 256 + tid;             // 6144 float4
    float4 v = *(const float4*)&xb[g * 4];
    ushort4 u;
    u.x = f2b(v.x); u.y = f2b(v.y); u.z = f2b(v.z); u.w = f2b(v.w);
    *(ushort4*)&xsh[g * 4] = u;
  }
  __syncthreads();

  // phase 2: xT writes — per c, 16 k's packed as 2 x uint4 (32 B)
  unsigned short* xT = (unsigned short*)(ws + WS_XT) + (size_t)b * NC * 512;
#pragma unroll
  for (int j = 0; j < 6; ++j) {
    int c = j * 256 + tid;
    unsigned vv[8];
#pragma unroll
    for (int k2 = 0; k2 < 8; ++k2) {
      unsigned lo = xsh[(2 * k2) * NC + c];
      unsigned hi = xsh[(2 * k2 + 1) * NC + c];
      vv[k2] = lo | (hi << 16);
    }
    uint4 w0; w0.x = vv[0]; w0.y = vv[1]; w0.z = vv[2]; w0.w = vv[3];
    uint4 w1; w1.x = vv[4]; w1.y = vv[5]; w1.z = vv[6]; w1.w = vv[7];
    *(uint4*)&xT[(size_t)c * 512 + i0] = w0;
    *(uint4*)&xT[(size_t)c * 512 + i0 + 8] = w1;
  }

  // phase 3: E. wave <-> node (4 passes), lane <-> f.
  int wave = tid >> 6, lane = tid & 63;
  const float* __restrict__ W2p = ws + 128;
  float rsw4 = 0.25f * ws[lane];
  float rswA = (lane < 10) ? 0.25f * ws[64 + lane] : 0.f;

  for (int p = 0; p < 4; ++p) {
    int node = p * 4 + wave;
    float xcol[24];
#pragma unroll
    for (int t = 0; t < 24; ++t) xcol[t] = b2f(xsh[node * NC + t * 64 + lane]);
    float S[24];
#pragma unroll
    for (int t = 0; t < 24; ++t) S[t] = xcol[t];
#pragma unroll
    for (int off = 32; off >= 1; off >>= 1) {
#pragma unroll
      for (int t = 0; t < 24; ++t) S[t] += __shfl_xor(S[t], off, 64);
    }
    float accv[24];
#pragma unroll
    for (int to = 0; to < 24; ++to) {
      float a = 0.f;
#pragma unroll
      for (int tp = 0; tp < 24; ++tp) a += xcol[tp] * W2p[to * 24 + tp];
      accv[to] = a;
    }
    // write own node's E row into ebuf (per-wave disjoint sections)
#pragma unroll
    for (int t = 0; t < 24; ++t) {
      float ev = 0.5f * xcol[t] + 0.25f * accv[t] + S[t] * rsw4;
      if (EPATH) eh[wave * NCF + t * 74 + lane] = f2b(ev);
      else       ebuf[wave * NCF + t * 74 + lane] = ev;
    }
#pragma unroll
    for (int t = 0; t < 24; ++t) {
      if (lane < 10) {
        float av = fmaxf(S[t] * rswA, 0.f);
        if (EPATH) eh[wave * NCF + t * 74 + 64 + lane] = f2b(av);
        else       ebuf[wave * NCF + t * 74 + 64 + lane] = av;
      }
    }
    __syncthreads();
    // stream ebuf out
    if (EPATH) {
      unsigned short* Eg = (unsigned short*)(ws + WS_E) +
                           ((size_t)(b * N_ + i0 + p * 4)) * NCF;
      const uint4* src = (const uint4*)eh;
      uint4* dst = (uint4*)Eg;
#pragma unroll
      for (int j = 0; j < 4; ++j) {
        int idx = j * 256 + tid;
        if (idx < 888) dst[idx] = src[idx];     // 4*1776 bf16 = 888 x 16 B
      }
      float* ob = out + ((size_t)(b * N_ + i0 + p * 4)) * NCF;
#pragma unroll
      for (int j = 0; j < 4; ++j) {
        int e = j * 256 + tid;
        if (e < 960) {                          // aug cols: final fp32
          int nd = e / 240, rem = e - nd * 240;
          int t = rem / 10, m = rem - t * 10;
          ob[(size_t)nd * NCF + t * 74 + 64 + m] = b2f(eh[nd * NCF + t * 74 + 64 + m]);
        }
      }
    } else {
      float* og = out + ((size_t)(b * N_ + i0 + p * 4)) * NCF;
#pragma unroll
      for (int j = 0; j < 7; ++j) {
        int idx = j * 256 + tid;
        if (idx < 1776) ((float4*)og)[idx] = ((const float4*)ebuf)[idx];
      }
    }
    __syncthreads();
  }
}

// gemm: acc = adjMod @ x  (adjMod already 0.125*sigma-scaled bf16)
// epilogue: out = relu(acc + E).  grid (12, 4, 32), 256 thr.
template <bool EPATH>
__global__ __launch_bounds__(256) void gemm_kernel(
    const float* __restrict__ ws, float* __restrict__ out) {
  const unsigned short* adjM = (const unsigned short*)(ws + WS_ADJ);
  const unsigned short* xT   = (const unsigned short*)(ws + WS_XT);
  __shared__ short As[128 * 32];
  __shared__ short Bs[128 * 32];

  int tid = threadIdx.x;
  int b  = blockIdx.z;
  int i0 = blockIdx.y * 128;
  int c0 = blockIdx.x * 128;
  int wave = tid >> 6, lane = tid & 63;
  int mw = (wave & 1) * 64, nw = (wave >> 1) * 64;
  int l15 = lane & 15, l4 = lane >> 4;

  floatx4 acc[4][4];
#pragma unroll
  for (int mt = 0; mt < 4; ++mt)
#pragma unroll
    for (int nt = 0; nt < 4; ++nt) acc[mt][nt] = (floatx4){0.f, 0.f, 0.f, 0.f};

  const size_t bRow = (size_t)b * NC;
  for (int k0 = 0; k0 < 512; k0 += 32) {
#pragma unroll
    for (int rep = 0; rep < 2; ++rep) {
      int chunk = rep * 256 + tid;       // 512 chunks of 8 bf16
      int r = chunk >> 2;
      int k8 = (chunk & 3) * 8;
      __builtin_amdgcn_global_load_lds(AS1(adjM + (size_t)(i0 + r) * 512 + k0 + k8),
                                       AS3(&As[chunk * 8]), 16, 0, 0);
      __builtin_amdgcn_global_load_lds(AS1(xT + (bRow + c0 + r) * 512 + k0 + k8),
                                       AS3(&Bs[chunk * 8]), 16, 0, 0);
    }
    __syncthreads();

    short8 af[4], bf[4];
#pragma unroll
    for (int mt = 0; mt < 4; ++mt)
      af[mt] = *(const short8*)&As[(mw + mt * 16 + l15) * 32 + l4 * 8];
#pragma unroll
    for (int nt = 0; nt < 4; ++nt)
      bf[nt] = *(const short8*)&Bs[(nw + nt * 16 + l15) * 32 + l4 * 8];
#pragma unroll
    for (int mt = 0; mt < 4; ++mt)
#pragma unroll
      for (int nt = 0; nt < 4; ++nt)
        acc[mt][nt] = __builtin_amdgcn_mfma_f32_16x16x32_bf16(af[mt], bf[nt], acc[mt][nt], 0, 0, 0);
    __syncthreads();
  }

  const unsigned short* Eb = (const unsigned short*)(ws + WS_E) + (size_t)b * N_ * NCF;
#pragma unroll
  for (int mt = 0; mt < 4; ++mt) {
#pragma unroll
    for (int nt = 0; nt < 4; ++nt) {
      int col = c0 + nw + nt * 16 + l15;
      int t = col >> 6, f = col & 63;
      int cofs = t * 74 + f;
#pragma unroll
      for (int r = 0; r < 4; ++r) {
        int row = i0 + mw + mt * 16 + l4 * 4 + r;
        size_t o = (size_t)(b * N_ + row) * NCF + cofs;
        float val;
        if (EPATH) val = acc[mt][nt][r] + b2f(Eb[(size_t)row * NCF + cofs]);
        else       val = out[o] + acc[mt][nt][r];
        out[o] = fmaxf(val, 0.f);
      }
    }
  }
}

extern "C" void kernel_launch(void* const* d_in, const int* in_sizes, int n_in,
                              void* d_out, int out_size, void* d_ws, size_t ws_size,
                              hipStream_t stream) {
  const float* x     = (const float*)d_in[0];
  const float* adj   = (const float*)d_in[1];
  const float* alpha = (const float*)d_in[2];
  const float* w     = (const float*)d_in[3];
  const float* d     = (const float*)d_in[4];
  const float* w2    = (const float*)d_in[5];
  const float* d2    = (const float*)d_in[6];
  float* out = (float*)d_out;
  float* ws  = (float*)d_ws;

  hipLaunchKernelGGL(params_kernel, dim3(1), dim3(256), 0, stream,
                     alpha, w, d, w2, d2, ws);
  hipLaunchKernelGGL(convert_adj_kernel, dim3(256), dim3(256), 0, stream, adj, ws);

  if (ws_size >= WS_BYTES_NEEDED) {
    hipLaunchKernelGGL((prep_kernel<true>), dim3(32, 32), dim3(256), 0, stream, x, ws, out);
    hipLaunchKernelGGL((gemm_kernel<true>), dim3(12, 4, B_), dim3(256), 0, stream, ws, out);
  } else {
    hipLaunchKernelGGL((prep_kernel<false>), dim3(32, 32), dim3(256), 0, stream, x, ws, out);
    hipLaunchKernelGGL((gemm_kernel<false>), dim3(12, 4, B_), dim3(256), 0, stream, ws, out);
  }
}

// Round 4
// 377.104 us; speedup vs baseline: 1.0389x; 1.0389x over previous
//
#include <hip/hip_runtime.h>
#include <hip/hip_bf16.h>
#include <cstdint>
#include <cstddef>

#define B_  32
#define N_  512
#define T_  24
#define F_  64
#define FA_ 74
#define NC  1536   // T_*F_
#define NCF 1776   // T_*FA_

typedef __attribute__((ext_vector_type(8))) short short8;
typedef __attribute__((ext_vector_type(4))) float floatx4;

// ws float-offset layout:
//  [0,74) rsW ; [128,704) W2' ; [768,1280) sigmoid(alpha)
//  WS_ADJ: adjMod bf16[512][512] (0.125*sigma_i*adj)
//  WS_XT : xTblk bf16[b][kb(64)][c(1536)][kk(8)]   (k = kb*8+kk)  ~50 MB
//  WS_E  : E bf16[b][i][t*74+f]                                   ~58 MB
#define WS_ADJ  1536
#define WS_XT   132608
#define WS_E    12715520
#define WS_BYTES_NEEDED (27264512ULL * 4ULL)

#define AS1(p) ((const __attribute__((address_space(1))) void*)(p))
#define AS3(p) ((__attribute__((address_space(3))) void*)(p))

__device__ __forceinline__ unsigned short f2b(float v) {
  __hip_bfloat16 h = __float2bfloat16(v);
  return *(unsigned short*)&h;
}
__device__ __forceinline__ float b2f(unsigned short u) {
  return __uint_as_float(((unsigned)u) << 16);
}

__global__ __launch_bounds__(256) void params_kernel(
    const float* __restrict__ alpha, const float* __restrict__ w,
    const float* __restrict__ d, const float* __restrict__ w2,
    const float* __restrict__ d2, float* __restrict__ ws) {
  __shared__ float cs[FA_];
  int tid = threadIdx.x;
  if (tid < FA_) {
    float s = 0.f;
    for (int n = 0; n < FA_; ++n) s += w[n * FA_ + tid];
    cs[tid] = s;
  }
  __syncthreads();
  if (tid < FA_) {
    float s = 0.f;
    for (int p = 0; p < FA_; ++p) {
      float dc = fminf(fmaxf(d[p], 0.f), 1.f);
      s += w[tid * FA_ + p] * dc * cs[p];
    }
    ws[tid] = s;
  }
  for (int e = tid; e < T_ * T_; e += 256) {
    int a = e / T_, b = e % T_;
    float s = 0.f;
    for (int p = 0; p < T_; ++p) {
      float dc = fminf(fmaxf(d2[p], 0.f), 1.f);
      s += w2[a * T_ + p] * dc * w2[b * T_ + p];
    }
    ws[128 + e] = s;
  }
  for (int i = tid; i < N_; i += 256) ws[768 + i] = 1.f / (1.f + __expf(-alpha[i]));
}

__global__ __launch_bounds__(256) void convert_adj_kernel(
    const float* __restrict__ adj, float* __restrict__ ws) {
  unsigned short* adjM = (unsigned short*)(ws + WS_ADJ);
  int g = (blockIdx.x * 256 + threadIdx.x) * 4;
  int i = g >> 9;
  float s = 0.125f * ws[768 + i];
  float4 v = *(const float4*)&adj[g];
  ushort4 u;
  u.x = f2b(s * v.x); u.y = f2b(s * v.y); u.z = f2b(s * v.z); u.w = f2b(s * v.w);
  *(ushort4*)&adjM[g] = u;
}

// prep: block = (kb slab of 8 nodes, b). Read x once ->
//   (a) xTblk[b][kb][c][0:8]  — contiguous 48KB/block, coalesced 32B/thread
//   (b) E bf16 (EPATH) or fp32-to-out (fallback)
//   (c) aug out cols (final relu'd fp32)
template <bool EPATH>
__global__ __launch_bounds__(256, 4) void prep_kernel(
    const float* __restrict__ x, float* __restrict__ ws, float* __restrict__ out) {
  __shared__ __align__(16) unsigned short xsh[8 * NC];            // 24576 B [k][c]
  __shared__ __align__(16) float ebuf[EPATH ? 2 * NCF : 4 * NCF]; // 14208 / 28416 B
  unsigned short* eh = (unsigned short*)ebuf;

  int tid = threadIdx.x;
  int b = blockIdx.y;
  int kb = blockIdx.x;
  int i0 = kb * 8;
  const float* xb = x + ((size_t)(b * N_ + i0)) * NC;

  // phase 1: 8 rows x 1536 fp32 -> bf16 LDS, linear
#pragma unroll
  for (int it = 0; it < 12; ++it) {
    int g = it * 256 + tid;          // 3072 float4
    float4 v = *(const float4*)&xb[g * 4];
    ushort4 u;
    u.x = f2b(v.x); u.y = f2b(v.y); u.z = f2b(v.z); u.w = f2b(v.w);
    *(ushort4*)&xsh[g * 4] = u;
  }
  __syncthreads();

  // phase 2: xTblk writes. thread -> c-pair; 8 conflict-free b32 LDS reads + packs;
  // two uint4 stores at cp*32 — fully coalesced.
  {
    unsigned short* xTs = (unsigned short*)(ws + WS_XT) + ((size_t)(b * 64 + kb)) * (NC * 8);
#pragma unroll
    for (int j = 0; j < 3; ++j) {
      int cp = j * 256 + tid;        // 0..767
      unsigned u[8];
#pragma unroll
      for (int k = 0; k < 8; ++k) u[k] = *(const unsigned*)&xsh[k * NC + cp * 2];
      uint4 w0, w1;
      w0.x = (u[0] & 0xffffu) | (u[1] << 16);
      w0.y = (u[2] & 0xffffu) | (u[3] << 16);
      w0.z = (u[4] & 0xffffu) | (u[5] << 16);
      w0.w = (u[6] & 0xffffu) | (u[7] << 16);
      w1.x = (u[0] >> 16) | (u[1] & 0xffff0000u);
      w1.y = (u[2] >> 16) | (u[3] & 0xffff0000u);
      w1.z = (u[4] >> 16) | (u[5] & 0xffff0000u);
      w1.w = (u[6] >> 16) | (u[7] & 0xffff0000u);
      *(uint4*)&xTs[(size_t)cp * 16] = w0;
      *(uint4*)&xTs[(size_t)cp * 16 + 8] = w1;
    }
  }

  // phase 3: E for 8 nodes, 2 passes of (wave<->node, lane<->f)
  int wave = tid >> 6, lane = tid & 63;
  const float* __restrict__ W2p = ws + 128;
  float rsw4 = 0.25f * ws[lane];
  float rswA = (lane < 10) ? 0.25f * ws[64 + lane] : 0.f;

  for (int p = 0; p < 2; ++p) {
    int node = p * 4 + wave;
    float xcol[24];
#pragma unroll
    for (int t = 0; t < 24; ++t) xcol[t] = b2f(xsh[node * NC + t * 64 + lane]);
    float S[24];
#pragma unroll
    for (int t = 0; t < 24; ++t) S[t] = xcol[t];
#pragma unroll
    for (int off = 32; off >= 1; off >>= 1) {
#pragma unroll
      for (int t = 0; t < 24; ++t) S[t] += __shfl_xor(S[t], off, 64);
    }
    float accv[24];
#pragma unroll
    for (int to = 0; to < 24; ++to) {
      float a = 0.f;
#pragma unroll
      for (int tp = 0; tp < 24; ++tp) a += xcol[tp] * W2p[to * 24 + tp];
      accv[to] = a;
    }
#pragma unroll
    for (int t = 0; t < 24; ++t) {
      float ev = 0.5f * xcol[t] + 0.25f * accv[t] + S[t] * rsw4;
      if (EPATH) eh[wave * NCF + t * 74 + lane] = f2b(ev);
      else       ebuf[wave * NCF + t * 74 + lane] = ev;
    }
#pragma unroll
    for (int t = 0; t < 24; ++t) {
      if (lane < 10) {
        float av = fmaxf(S[t] * rswA, 0.f);
        if (EPATH) eh[wave * NCF + t * 74 + 64 + lane] = f2b(av);
        else       ebuf[wave * NCF + t * 74 + 64 + lane] = av;
      }
    }
    __syncthreads();
    if (EPATH) {
      unsigned short* Eg = (unsigned short*)(ws + WS_E) +
                           ((size_t)(b * N_ + i0 + p * 4)) * NCF;
      const uint4* src = (const uint4*)eh;
      uint4* dst = (uint4*)Eg;
#pragma unroll
      for (int j = 0; j < 4; ++j) {
        int idx = j * 256 + tid;
        if (idx < 888) dst[idx] = src[idx];       // 4*1776 bf16 = 888 x 16 B
      }
      float* ob = out + ((size_t)(b * N_ + i0 + p * 4)) * NCF;
#pragma unroll
      for (int j = 0; j < 4; ++j) {
        int e = j * 256 + tid;
        if (e < 960) {
          int nd = e / 240, rem = e - nd * 240;
          int t = rem / 10, m = rem - t * 10;
          ob[(size_t)nd * NCF + t * 74 + 64 + m] = b2f(eh[nd * NCF + t * 74 + 64 + m]);
        }
      }
    } else {
      float* og = out + ((size_t)(b * N_ + i0 + p * 4)) * NCF;
#pragma unroll
      for (int j = 0; j < 7; ++j) {
        int idx = j * 256 + tid;
        if (idx < 1776) ((float4*)og)[idx] = ((const float4*)ebuf)[idx];
      }
    }
    __syncthreads();
  }
}

// gemm: acc = adjMod @ x via xTblk; epilogue out = relu(acc + E)
// B staged as 4 regions [128 c][16 B] <- kb0..kb0+3; region = l4 of b-frag.
template <bool EPATH>
__global__ __launch_bounds__(256) void gemm_kernel(
    const float* __restrict__ ws, float* __restrict__ out) {
  const unsigned short* adjM = (const unsigned short*)(ws + WS_ADJ);
  const unsigned short* xT   = (const unsigned short*)(ws + WS_XT);
  __shared__ short As[128 * 32];      // [i][32k] pitch 64 B
  __shared__ short Bs[4 * 128 * 8];   // region r: [c][8k] at short-offset r*1024

  int tid = threadIdx.x;
  int b  = blockIdx.z;
  int i0 = blockIdx.y * 128;
  int c0 = blockIdx.x * 128;
  int wave = tid >> 6, lane = tid & 63;
  int mw = (wave & 1) * 64, nw = (wave >> 1) * 64;
  int l15 = lane & 15, l4 = lane >> 4;

  floatx4 acc[4][4];
#pragma unroll
  for (int mt = 0; mt < 4; ++mt)
#pragma unroll
    for (int nt = 0; nt < 4; ++nt) acc[mt][nt] = (floatx4){0.f, 0.f, 0.f, 0.f};

  const size_t slabBase = (size_t)b * 64;
  for (int k0 = 0; k0 < 512; k0 += 32) {
    int kb0 = k0 >> 3;
#pragma unroll
    for (int rep = 0; rep < 2; ++rep) {
      int chunk = rep * 256 + tid;       // 512 units of 16 B each, A and B
      int r = chunk >> 2, k8 = (chunk & 3) * 8;
      __builtin_amdgcn_global_load_lds(AS1(adjM + (size_t)(i0 + r) * 512 + k0 + k8),
                                       AS3(&As[chunk * 8]), 16, 0, 0);
      int rr = chunk >> 7, c = chunk & 127;
      __builtin_amdgcn_global_load_lds(
          AS1(xT + ((slabBase + kb0 + rr) * NC + c0 + c) * 8),
          AS3(&Bs[rr * 1024 + c * 8]), 16, 0, 0);
    }
    __syncthreads();

    short8 af[4], bf[4];
#pragma unroll
    for (int mt = 0; mt < 4; ++mt)
      af[mt] = *(const short8*)&As[(mw + mt * 16 + l15) * 32 + l4 * 8];
#pragma unroll
    for (int nt = 0; nt < 4; ++nt)
      bf[nt] = *(const short8*)&Bs[l4 * 1024 + (nw + nt * 16 + l15) * 8];
#pragma unroll
    for (int mt = 0; mt < 4; ++mt)
#pragma unroll
      for (int nt = 0; nt < 4; ++nt)
        acc[mt][nt] = __builtin_amdgcn_mfma_f32_16x16x32_bf16(af[mt], bf[nt], acc[mt][nt], 0, 0, 0);
    __syncthreads();
  }

  const unsigned short* Eb = (const unsigned short*)(ws + WS_E) + (size_t)b * N_ * NCF;
#pragma unroll
  for (int mt = 0; mt < 4; ++mt) {
#pragma unroll
    for (int nt = 0; nt < 4; ++nt) {
      int col = c0 + nw + nt * 16 + l15;
      int t = col >> 6, f = col & 63;
      int cofs = t * 74 + f;
#pragma unroll
      for (int r = 0; r < 4; ++r) {
        int row = i0 + mw + mt * 16 + l4 * 4 + r;
        size_t o = (size_t)(b * N_ + row) * NCF + cofs;
        float val;
        if (EPATH) val = acc[mt][nt][r] + b2f(Eb[(size_t)row * NCF + cofs]);
        else       val = out[o] + acc[mt][nt][r];
        out[o] = fmaxf(val, 0.f);
      }
    }
  }
}

extern "C" void kernel_launch(void* const* d_in, const int* in_sizes, int n_in,
                              void* d_out, int out_size, void* d_ws, size_t ws_size,
                              hipStream_t stream) {
  const float* x     = (const float*)d_in[0];
  const float* adj   = (const float*)d_in[1];
  const float* alpha = (const float*)d_in[2];
  const float* w     = (const float*)d_in[3];
  const float* d     = (const float*)d_in[4];
  const float* w2    = (const float*)d_in[5];
  const float* d2    = (const float*)d_in[6];
  float* out = (float*)d_out;
  float* ws  = (float*)d_ws;

  hipLaunchKernelGGL(params_kernel, dim3(1), dim3(256), 0, stream,
                     alpha, w, d, w2, d2, ws);
  hipLaunchKernelGGL(convert_adj_kernel, dim3(256), dim3(256), 0, stream, adj, ws);

  if (ws_size >= WS_BYTES_NEEDED) {
    hipLaunchKernelGGL((prep_kernel<true>), dim3(64, 32), dim3(256), 0, stream, x, ws, out);
    hipLaunchKernelGGL((gemm_kernel<true>), dim3(12, 4, B_), dim3(256), 0, stream, ws, out);
  } else {
    hipLaunchKernelGGL((prep_kernel<false>), dim3(64, 32), dim3(256), 0, stream, x, ws, out);
    hipLaunchKernelGGL((gemm_kernel<false>), dim3(12, 4, B_), dim3(256), 0, stream, ws, out);
  }
}

// Round 5
// 345.993 us; speedup vs baseline: 1.1324x; 1.0899x over previous
//
#include <hip/hip_runtime.h>
#include <hip/hip_bf16.h>
#include <cstdint>
#include <cstddef>

#define B_  32
#define N_  512
#define T_  24
#define F_  64
#define FA_ 74
#define NC  1536   // T_*F_
#define NCF 1776   // T_*FA_

typedef __attribute__((ext_vector_type(8))) short short8;
typedef __attribute__((ext_vector_type(4))) float floatx4;

// ws float-offset layout:
//  [0,74) rsW ; [128,704) C2 = 0.25*W2' + 0.5*I ; [768,1280) sigmoid(alpha)
//  WS_ADJ: adjMod bf16[512][512] (0.125*sigma_i*adj)
//  WS_XT : xTblk bf16[b][kb(64)][c(1536)][kk(8)]   (k = kb*8+kk)  ~50 MB
//  WS_E  : E bf16[b][i][t*74+f]                                   ~58 MB
#define WS_ADJ  1536
#define WS_XT   132608
#define WS_E    12715520
#define WS_BYTES_NEEDED (27264512ULL * 4ULL)

#define AS1(p) ((const __attribute__((address_space(1))) void*)(p))
#define AS3(p) ((__attribute__((address_space(3))) void*)(p))

__device__ __forceinline__ unsigned short f2b(float v) {
  __hip_bfloat16 h = __float2bfloat16(v);
  return *(unsigned short*)&h;
}
__device__ __forceinline__ float b2f(unsigned short u) {
  return __uint_as_float(((unsigned)u) << 16);
}

__global__ __launch_bounds__(256) void params_kernel(
    const float* __restrict__ alpha, const float* __restrict__ w,
    const float* __restrict__ d, const float* __restrict__ w2,
    const float* __restrict__ d2, float* __restrict__ ws) {
  __shared__ float cs[FA_];
  int tid = threadIdx.x;
  if (tid < FA_) {
    float s = 0.f;
    for (int n = 0; n < FA_; ++n) s += w[n * FA_ + tid];
    cs[tid] = s;
  }
  __syncthreads();
  if (tid < FA_) {
    float s = 0.f;
    for (int p = 0; p < FA_; ++p) {
      float dc = fminf(fmaxf(d[p], 0.f), 1.f);
      s += w[tid * FA_ + p] * dc * cs[p];
    }
    ws[tid] = s;
  }
  for (int e = tid; e < T_ * T_; e += 256) {
    int a = e / T_, b = e % T_;
    float s = 0.f;
    for (int p = 0; p < T_; ++p) {
      float dc = fminf(fmaxf(d2[p], 0.f), 1.f);
      s += w2[a * T_ + p] * dc * w2[b * T_ + p];
    }
    ws[128 + e] = 0.25f * s + ((a == b) ? 0.5f : 0.f);   // C2
  }
  for (int i = tid; i < N_; i += 256) ws[768 + i] = 1.f / (1.f + __expf(-alpha[i]));
}

__global__ __launch_bounds__(256) void convert_adj_kernel(
    const float* __restrict__ adj, const float* __restrict__ wsc,
    unsigned short* __restrict__ adjM) {
  int g = (blockIdx.x * 256 + threadIdx.x) * 4;
  int i = g >> 9;
  float s = 0.125f * wsc[768 + i];
  float4 v = *(const float4*)&adj[g];
  ushort4 u;
  u.x = f2b(s * v.x); u.y = f2b(s * v.y); u.z = f2b(s * v.z); u.w = f2b(s * v.w);
  *(ushort4*)&adjM[g] = u;
}

// prep: block = (8-node slab, b). Read x once ->
//   (a) xTblk slab — coalesced 32B/thread stores
//   (b) E = C2-tmix + S*rsW4 (bf16 to Eg if EPATH, fp32 to out if not)
//   (c) aug out cols (final relu'd fp32, straight to out)
// LDS 24.6 KB only; no ebuf, no phase-3 barriers.
template <bool EPATH>
__global__ __launch_bounds__(256) void prep_kernel(
    const float* __restrict__ x, const float* __restrict__ wsc,
    unsigned short* __restrict__ xTg, unsigned short* __restrict__ Eg,
    float* __restrict__ out) {
  __shared__ __align__(16) unsigned short xsh[8 * NC];   // 24576 B [k][c]

  int tid = threadIdx.x;
  int b = blockIdx.y;
  int kb = blockIdx.x;
  int i0 = kb * 8;
  const float* xb = x + ((size_t)(b * N_ + i0)) * NC;

  // phase 1: 8 rows x 1536 fp32 -> bf16 LDS, linear
#pragma unroll
  for (int it = 0; it < 12; ++it) {
    int g = it * 256 + tid;          // 3072 float4
    float4 v = *(const float4*)&xb[g * 4];
    ushort4 u;
    u.x = f2b(v.x); u.y = f2b(v.y); u.z = f2b(v.z); u.w = f2b(v.w);
    *(ushort4*)&xsh[g * 4] = u;
  }
  __syncthreads();

  // phase 2: xTblk slab — thread -> c-pair, 8 b32 LDS reads + packs, 2 uint4 stores
  {
    unsigned short* xTs = xTg + ((size_t)(b * 64 + kb)) * (NC * 8);
#pragma unroll
    for (int j = 0; j < 3; ++j) {
      int cp = j * 256 + tid;        // 0..767
      unsigned u[8];
#pragma unroll
      for (int k = 0; k < 8; ++k) u[k] = *(const unsigned*)&xsh[k * NC + cp * 2];
      uint4 w0, w1;
      w0.x = (u[0] & 0xffffu) | (u[1] << 16);
      w0.y = (u[2] & 0xffffu) | (u[3] << 16);
      w0.z = (u[4] & 0xffffu) | (u[5] << 16);
      w0.w = (u[6] & 0xffffu) | (u[7] << 16);
      w1.x = (u[0] >> 16) | (u[1] & 0xffff0000u);
      w1.y = (u[2] >> 16) | (u[3] & 0xffff0000u);
      w1.z = (u[4] >> 16) | (u[5] & 0xffff0000u);
      w1.w = (u[6] >> 16) | (u[7] & 0xffff0000u);
      *(uint4*)&xTs[(size_t)cp * 16] = w0;
      *(uint4*)&xTs[(size_t)cp * 16 + 8] = w1;
    }
  }

  // phase 3: E for 8 nodes, 2 passes (wave<->node, lane<->f). No barriers.
  int wave = tid >> 6, lane = tid & 63;
  const float* __restrict__ C2 = wsc + 128;    // hoistable s_loads now
  float rsw4 = 0.25f * wsc[lane];
  float rswA = (lane < 10) ? 0.25f * wsc[64 + lane] : 0.f;

#pragma unroll
  for (int p = 0; p < 2; ++p) {
    int node = p * 4 + wave;
    int row = b * N_ + i0 + node;
    float xcol[24];
#pragma unroll
    for (int t = 0; t < 24; ++t) xcol[t] = b2f(xsh[node * NC + t * 64 + lane]);
    float S[24];
#pragma unroll
    for (int t = 0; t < 24; ++t) S[t] = xcol[t];
#pragma unroll
    for (int off = 32; off >= 1; off >>= 1) {
#pragma unroll
      for (int t = 0; t < 24; ++t) S[t] += __shfl_xor(S[t], off, 64);
    }
#pragma unroll
    for (int to = 0; to < 24; ++to) {
      float a = 0.f;
#pragma unroll
      for (int tp = 0; tp < 24; ++tp) a += xcol[tp] * C2[to * 24 + tp];
      float ev = a + S[to] * rsw4;
      if (EPATH) Eg[(size_t)row * NCF + to * 74 + lane] = f2b(ev);
      else       out[(size_t)row * NCF + to * 74 + lane] = ev;
    }
    if (lane < 10) {
#pragma unroll
      for (int t = 0; t < 24; ++t) {
        out[(size_t)row * NCF + t * 74 + 64 + lane] = fmaxf(S[t] * rswA, 0.f);
      }
    }
  }
}

// gemm: acc = adjMod @ x via xTblk; epilogue out = relu(acc + E)
template <bool EPATH>
__global__ __launch_bounds__(256) void gemm_kernel(
    const unsigned short* __restrict__ adjM, const unsigned short* __restrict__ xT,
    const unsigned short* __restrict__ Eg, float* __restrict__ out) {
  __shared__ short As[128 * 32];      // [i][32k] pitch 64 B
  __shared__ short Bs[4 * 128 * 8];   // region r: [c][8k] at short-offset r*1024

  int tid = threadIdx.x;
  int b  = blockIdx.z;
  int i0 = blockIdx.y * 128;
  int c0 = blockIdx.x * 128;
  int wave = tid >> 6, lane = tid & 63;
  int mw = (wave & 1) * 64, nw = (wave >> 1) * 64;
  int l15 = lane & 15, l4 = lane >> 4;

  floatx4 acc[4][4];
#pragma unroll
  for (int mt = 0; mt < 4; ++mt)
#pragma unroll
    for (int nt = 0; nt < 4; ++nt) acc[mt][nt] = (floatx4){0.f, 0.f, 0.f, 0.f};

  const size_t slabBase = (size_t)b * 64;
  for (int k0 = 0; k0 < 512; k0 += 32) {
    int kb0 = k0 >> 3;
#pragma unroll
    for (int rep = 0; rep < 2; ++rep) {
      int chunk = rep * 256 + tid;       // 512 units of 16 B each, A and B
      int r = chunk >> 2, k8 = (chunk & 3) * 8;
      __builtin_amdgcn_global_load_lds(AS1(adjM + (size_t)(i0 + r) * 512 + k0 + k8),
                                       AS3(&As[chunk * 8]), 16, 0, 0);
      int rr = chunk >> 7, c = chunk & 127;
      __builtin_amdgcn_global_load_lds(
          AS1(xT + ((slabBase + kb0 + rr) * NC + c0 + c) * 8),
          AS3(&Bs[rr * 1024 + c * 8]), 16, 0, 0);
    }
    __syncthreads();

    short8 af[4], bf[4];
#pragma unroll
    for (int mt = 0; mt < 4; ++mt)
      af[mt] = *(const short8*)&As[(mw + mt * 16 + l15) * 32 + l4 * 8];
#pragma unroll
    for (int nt = 0; nt < 4; ++nt)
      bf[nt] = *(const short8*)&Bs[l4 * 1024 + (nw + nt * 16 + l15) * 8];
#pragma unroll
    for (int mt = 0; mt < 4; ++mt)
#pragma unroll
      for (int nt = 0; nt < 4; ++nt)
        acc[mt][nt] = __builtin_amdgcn_mfma_f32_16x16x32_bf16(af[mt], bf[nt], acc[mt][nt], 0, 0, 0);
    __syncthreads();
  }

  const unsigned short* Eb = Eg + (size_t)b * N_ * NCF;
#pragma unroll
  for (int mt = 0; mt < 4; ++mt) {
#pragma unroll
    for (int nt = 0; nt < 4; ++nt) {
      int col = c0 + nw + nt * 16 + l15;
      int t = col >> 6, f = col & 63;
      int cofs = t * 74 + f;
#pragma unroll
      for (int r = 0; r < 4; ++r) {
        int row = i0 + mw + mt * 16 + l4 * 4 + r;
        size_t o = (size_t)(b * N_ + row) * NCF + cofs;
        float val;
        if (EPATH) val = acc[mt][nt][r] + b2f(Eb[(size_t)row * NCF + cofs]);
        else       val = out[o] + acc[mt][nt][r];
        out[o] = fmaxf(val, 0.f);
      }
    }
  }
}

extern "C" void kernel_launch(void* const* d_in, const int* in_sizes, int n_in,
                              void* d_out, int out_size, void* d_ws, size_t ws_size,
                              hipStream_t stream) {
  const float* x     = (const float*)d_in[0];
  const float* adj   = (const float*)d_in[1];
  const float* alpha = (const float*)d_in[2];
  const float* w     = (const float*)d_in[3];
  const float* d     = (const float*)d_in[4];
  const float* w2    = (const float*)d_in[5];
  const float* d2    = (const float*)d_in[6];
  float* out = (float*)d_out;
  float* ws  = (float*)d_ws;
  unsigned short* adjM = (unsigned short*)(ws + WS_ADJ);
  unsigned short* xT   = (unsigned short*)(ws + WS_XT);
  unsigned short* Eg   = (unsigned short*)(ws + WS_E);

  hipLaunchKernelGGL(params_kernel, dim3(1), dim3(256), 0, stream,
                     alpha, w, d, w2, d2, ws);
  hipLaunchKernelGGL(convert_adj_kernel, dim3(256), dim3(256), 0, stream,
                     adj, ws, adjM);

  if (ws_size >= WS_BYTES_NEEDED) {
    hipLaunchKernelGGL((prep_kernel<true>), dim3(64, 32), dim3(256), 0, stream,
                       x, ws, xT, Eg, out);
    hipLaunchKernelGGL((gemm_kernel<true>), dim3(12, 4, B_), dim3(256), 0, stream,
                       adjM, xT, Eg, out);
  } else {
    hipLaunchKernelGGL((prep_kernel<false>), dim3(64, 32), dim3(256), 0, stream,
                       x, ws, xT, Eg, out);
    hipLaunchKernelGGL((gemm_kernel<false>), dim3(12, 4, B_), dim3(256), 0, stream,
                       adjM, xT, Eg, out);
  }
}